// Round 2
// baseline (2324.702 us; speedup 1.0000x reference)
//
#include <hip/hip_runtime.h>
#include <math.h>

#define B_TOT   131072
#define S_DIM   274
#define H1_DIM  256
#define M_EMB   6
#define M_POP   8
#define D_DIM   128
#define A_DIM   30
#define NE_DIM  768
#define TILE_R  64
#define KB      16

__device__ __forceinline__ float sigmf(float x){ return 1.0f/(1.0f+__expf(-x)); }

// ---------- k0: precompute Kn (normalized proto keys) and conc[M][A] ----------
__global__ void k0_precompute(const float* __restrict__ proto,
                              const float* __restrict__ wd1, const float* __restrict__ bd1,
                              const float* __restrict__ wd2, const float* __restrict__ bd2,
                              float* __restrict__ Kn, float* __restrict__ conc)
{
    __shared__ float sHd[M_POP][D_DIM];
    const int t = threadIdx.x;
    const int j = t >> 5, lane = t & 31;
    float ss = 0.f;
    for (int q = lane; q < D_DIM; q += 32){ float v = proto[j*D_DIM+q]; ss += v*v; }
    #pragma unroll
    for (int mk = 16; mk >= 1; mk >>= 1) ss += __shfl_xor(ss, mk, 64);
    float inv = 1.0f / (sqrtf(ss) + 1e-8f);
    for (int q = lane; q < D_DIM; q += 32) Kn[j*D_DIM+q] = proto[j*D_DIM+q]*inv;
    for (int h = lane; h < D_DIM; h += 32){
        float acc = bd1[j*D_DIM+h];
        for (int d = 0; d < D_DIM; ++d)
            acc = fmaf(proto[j*D_DIM+d], wd1[(j*D_DIM+d)*D_DIM + h], acc);
        sHd[j][h] = fmaxf(acc, 0.f);
    }
    __syncthreads();
    if (t < M_POP*A_DIM){
        int jj = t / A_DIM, a = t - jj*A_DIM;
        float acc = bd2[jj*A_DIM + a];
        for (int h = 0; h < D_DIM; ++h)
            acc = fmaf(sHd[jj][h], wd2[(jj*D_DIM+h)*A_DIM + a], acc);
        float sp;
        if (acc > 20.f)       sp = acc;
        else if (acc < -20.f) sp = expf(acc);
        else                  sp = log1pf(expf(acc));
        conc[jj*A_DIM + a] = sp;
    }
}

// ---------- k1: h1 = relu(LN(state@we1+be1)) ; aux: crisis level + danger sims ----------
__global__ __launch_bounds__(256)
void k1_h1_aux(const float* __restrict__ state,
               const float* __restrict__ we1, const float* __restrict__ be1,
               const float* __restrict__ lng, const float* __restrict__ lnb,
               const float* __restrict__ wt,  const float* __restrict__ bt,
               const float* __restrict__ wc,  const float* __restrict__ bc,
               const float* __restrict__ crisis_bias, const float* __restrict__ Kn,
               float* __restrict__ h1, float* __restrict__ crisL, float* __restrict__ dsimO)
{
    __shared__ float sA[2][KB][TILE_R];
    __shared__ float sB[2][KB][H1_DIM];
    const int tid = threadIdx.x;
    const int tx  = tid & 31, ty = tid >> 5;
    const int row0 = blockIdx.x * TILE_R;

    // ---- aux phase: 4 threads per row ----
    {
        const int r    = tid >> 2;
        const int part = tid & 3;
        const float* srow = state + (size_t)(row0 + r) * S_DIM;
        float bal = srow[0];
        float sp = 0.f;
        for (int q = 1; q <= 30; ++q) sp += srow[q];
        float pmean = sp * (1.0f/30.0f);
        float sv = 0.f, tv = bal;
        for (int q = 1; q <= 30; ++q){
            float p = srow[q];
            float d = p - pmean; sv = fmaf(d,d,sv);
            tv = fmaf(p, srow[q+30], tv);
        }
        float pstd = sqrtf(sv * (1.0f/29.0f)) + 1e-8f;
        float cash = bal / (tv + 1e-8f);
        float mf[12];
        mf[0]=bal; mf[1]=pmean; mf[2]=pstd; mf[3]=cash;
        mf[4]=srow[61];  mf[5]=srow[91];   mf[6]=srow[121]; mf[7]=srow[151];
        mf[8]=srow[181]; mf[9]=srow[211];  mf[10]=srow[241]; mf[11]=srow[271];
        float csum=0.f, nsum=0.f;
        float ssum[M_POP];
        #pragma unroll
        for (int jj=0;jj<M_POP;++jj) ssum[jj]=0.f;
        for (int d0 = 0; d0 < 32; ++d0){
            int d = part*32 + d0;
            float a = bt[d];
            #pragma unroll
            for (int f = 0; f < 12; ++f) a = fmaf(mf[f], wt[f*D_DIM + d], a);
            float ht = fmaxf(a, 0.f);
            csum = fmaf(ht, wc[d], csum);
            nsum = fmaf(ht, ht, nsum);
            #pragma unroll
            for (int jj=0;jj<M_POP;++jj) ssum[jj] = fmaf(ht, Kn[jj*D_DIM + d], ssum[jj]);
        }
        #pragma unroll
        for (int mk=1; mk<=2; mk<<=1){
            csum += __shfl_xor(csum, mk, 64);
            nsum += __shfl_xor(nsum, mk, 64);
            #pragma unroll
            for (int jj=0;jj<M_POP;++jj) ssum[jj] += __shfl_xor(ssum[jj], mk, 64);
        }
        if (part == 0){
            float cb  = sigmf(csum + bc[0]);
            float dss = sigmf(srow[272]*10.0f);
            float cvs = sigmf(fabsf(srow[273])*50.0f);
            float cl  = 0.6f*cb + 0.25f*dss + 0.15f*cvs + crisis_bias[0];
            crisL[row0+r] = cl;
            float invd = 1.0f/(sqrtf(nsum) + 1e-8f);
            #pragma unroll
            for (int jj=0;jj<M_POP;++jj) dsimO[(size_t)(row0+r)*M_POP + jj] = ssum[jj]*invd;
        }
    }

    // ---- GEMM1: 64x256 tile, 8x8 per thread, dbuf LDS ----
    float acc[8][8];
    #pragma unroll
    for (int r=0;r<8;++r)
        #pragma unroll
        for (int c=0;c<8;++c) acc[r][c]=0.f;

    const int la_row = tid >> 2;
    const int la_kk  = (tid & 3) * 4;
    const int lb_kk  = tid >> 4;
    const int lb_col = (tid & 15) * 16;
    const int NCH = (S_DIM + KB - 1) / KB;   // 18

    float2 va[2]; float4 vb[4];
    {   // prologue (chunk 0 fully in range)
        const float* pA = state + (size_t)(row0+la_row)*S_DIM + la_kk;
        va[0] = *(const float2*)(pA);
        va[1] = *(const float2*)(pA+2);
        const float* pB = we1 + (size_t)lb_kk*H1_DIM + lb_col;
        #pragma unroll
        for (int i=0;i<4;++i) vb[i] = *(const float4*)(pB + 4*i);
    }
    sA[0][la_kk  ][la_row]=va[0].x; sA[0][la_kk+1][la_row]=va[0].y;
    sA[0][la_kk+2][la_row]=va[1].x; sA[0][la_kk+3][la_row]=va[1].y;
    #pragma unroll
    for (int i=0;i<4;++i) *(float4*)&sB[0][lb_kk][lb_col+4*i] = vb[i];
    __syncthreads();

    for (int ch = 0; ch < NCH; ++ch){
        const int buf = ch & 1;
        const bool pf = (ch + 1 < NCH);
        if (pf){
            const int k0 = (ch+1)*KB;
            const int ka = k0 + la_kk;
            const float* pA = state + (size_t)(row0+la_row)*S_DIM + ka;
            va[0] = (ka   < S_DIM) ? *(const float2*)(pA)   : make_float2(0.f,0.f);
            va[1] = (ka+2 < S_DIM) ? *(const float2*)(pA+2) : make_float2(0.f,0.f);
            const int kb = k0 + lb_kk;
            const float* pB = we1 + (size_t)kb*H1_DIM + lb_col;
            if (kb < S_DIM){
                #pragma unroll
                for (int i=0;i<4;++i) vb[i] = *(const float4*)(pB + 4*i);
            } else {
                #pragma unroll
                for (int i=0;i<4;++i) vb[i] = make_float4(0.f,0.f,0.f,0.f);
            }
        }
        #pragma unroll
        for (int kk = 0; kk < KB; ++kk){
            float4 a0 = *(const float4*)&sA[buf][kk][ty*8];
            float4 a1 = *(const float4*)&sA[buf][kk][ty*8+4];
            float a[8] = {a0.x,a0.y,a0.z,a0.w,a1.x,a1.y,a1.z,a1.w};
            float b[8];
            #pragma unroll
            for (int c=0;c<8;++c) b[c] = sB[buf][kk][tx + 32*c];
            #pragma unroll
            for (int r=0;r<8;++r)
                #pragma unroll
                for (int c=0;c<8;++c) acc[r][c] = fmaf(a[r], b[c], acc[r][c]);
        }
        if (pf){
            const int nb = buf ^ 1;
            sA[nb][la_kk  ][la_row]=va[0].x; sA[nb][la_kk+1][la_row]=va[0].y;
            sA[nb][la_kk+2][la_row]=va[1].x; sA[nb][la_kk+3][la_row]=va[1].y;
            #pragma unroll
            for (int i=0;i<4;++i) *(float4*)&sB[nb][lb_kk][lb_col+4*i] = vb[i];
        }
        __syncthreads();
    }

    // ---- bias + LayerNorm + relu + store ----
    float gcol[8], bbcol[8], becol[8];
    #pragma unroll
    for (int c=0;c<8;++c){
        int col = tx + 32*c;
        becol[c] = be1[col]; gcol[c] = lng[col]; bbcol[c] = lnb[col];
    }
    #pragma unroll
    for (int r=0;r<8;++r){
        float s=0.f, sq=0.f;
        #pragma unroll
        for (int c=0;c<8;++c){
            float h = acc[r][c] + becol[c];
            acc[r][c] = h; s += h; sq = fmaf(h,h,sq);
        }
        #pragma unroll
        for (int mk=1; mk<=16; mk<<=1){ s += __shfl_xor(s,mk,64); sq += __shfl_xor(sq,mk,64); }
        float mu  = s  * (1.0f/256.0f);
        float var = sq * (1.0f/256.0f) - mu*mu;
        float rstd = rsqrtf(var + 1e-5f);
        float* orow = h1 + (size_t)(row0 + ty*8 + r) * H1_DIM;
        #pragma unroll
        for (int c=0;c<8;++c){
            float vv = (acc[r][c]-mu)*rstd*gcol[c] + bbcol[c];
            orow[tx + 32*c] = fmaxf(vv, 0.f);
        }
    }
}

// ---------- k2: E in 3 passes of 256 cols (2 panels each) -> sim/norm ; sinkhorn ; blend ; action ----------
// Manual LDS layout (floats):
//   sA   [2][KB][TILE_R]      2048   @ 0        (sAct overlaps here after GEMM passes)
//   sB   [2][KB][256]         8192   @ 2048
//   sKn  [8][128]             1024   @ 10240
//   sSim [64][6][8]           3072   @ 11264
//   sNrm [64][6]               384   @ 14336
//   sConc[240]                 240   @ 14720
//   total 14960 floats = 59.8 KB -> 2 blocks/CU
#define SMEM_TOT 14960
__global__ __launch_bounds__(256)
void k2_emb_sink_out(const float* __restrict__ h1,
                     const float* __restrict__ we2, const float* __restrict__ be2,
                     const float* __restrict__ Kn,  const float* __restrict__ conc,
                     const float* __restrict__ crisL, const float* __restrict__ dsimI,
                     const float* __restrict__ fitness, const float* __restrict__ w_prev,
                     float* __restrict__ out)
{
    __shared__ float smem[SMEM_TOT];
    float* sA    = smem;                    // [2][KB][64]
    float* sB    = smem + 2048;             // [2][KB][256]
    float* sKn   = smem + 10240;            // [8][128]
    float* sSim  = smem + 11264;            // [64][6][8]
    float* sNrm  = smem + 14336;            // [64][6]
    float* sConc = smem + 14720;            // [240]
    float* sAct  = smem;                    // overlap sA, [64*30]

    const int tid = threadIdx.x;
    const int tx = tid & 31, ty = tid >> 5;
    const int row0 = blockIdx.x * TILE_R;

    for (int q = tid; q < M_POP*D_DIM; q += 256) sKn[q] = Kn[q];
    for (int q = tid; q < M_POP*A_DIM; q += 256) sConc[q] = conc[q];

    const int la_row = tid >> 2;
    const int la_kk  = (tid & 3) * 4;
    const int lb_kk  = tid >> 4;
    const int lb_col = (tid & 15) * 16;
    const int NCH = H1_DIM / KB;   // 16

    for (int p2 = 0; p2 < 3; ++p2){
        const int c0 = p2 * 256;
        float acc[8][8];
        #pragma unroll
        for (int r=0;r<8;++r)
            #pragma unroll
            for (int c=0;c<8;++c) acc[r][c]=0.f;

        float4 va; float4 vb[4];
        {
            va = *(const float4*)(h1 + (size_t)(row0+la_row)*H1_DIM + la_kk);
            const float* pB = we2 + (size_t)lb_kk*NE_DIM + c0 + lb_col;
            #pragma unroll
            for (int i=0;i<4;++i) vb[i] = *(const float4*)(pB + 4*i);
        }
        sA[(la_kk  )*TILE_R + la_row]=va.x; sA[(la_kk+1)*TILE_R + la_row]=va.y;
        sA[(la_kk+2)*TILE_R + la_row]=va.z; sA[(la_kk+3)*TILE_R + la_row]=va.w;
        #pragma unroll
        for (int i=0;i<4;++i) *(float4*)&sB[lb_kk*256 + lb_col + 4*i] = vb[i];
        __syncthreads();

        for (int ch = 0; ch < NCH; ++ch){
            const int buf = ch & 1;
            const bool pf = (ch+1 < NCH);
            if (pf){
                const int k0 = (ch+1)*KB;
                va = *(const float4*)(h1 + (size_t)(row0+la_row)*H1_DIM + k0 + la_kk);
                const float* pB = we2 + (size_t)(k0+lb_kk)*NE_DIM + c0 + lb_col;
                #pragma unroll
                for (int i=0;i<4;++i) vb[i] = *(const float4*)(pB + 4*i);
            }
            const float* bufA = sA + buf*KB*TILE_R;
            const float* bufB = sB + buf*KB*256;
            #pragma unroll
            for (int kk=0; kk<KB; ++kk){
                float4 a0 = *(const float4*)&bufA[kk*TILE_R + ty*8];
                float4 a1 = *(const float4*)&bufA[kk*TILE_R + ty*8+4];
                float a[8] = {a0.x,a0.y,a0.z,a0.w,a1.x,a1.y,a1.z,a1.w};
                float b[8];
                #pragma unroll
                for (int c=0;c<8;++c) b[c] = bufB[kk*256 + tx + 32*c];
                #pragma unroll
                for (int r=0;r<8;++r)
                    #pragma unroll
                    for (int c=0;c<8;++c) acc[r][c] = fmaf(a[r], b[c], acc[r][c]);
            }
            if (pf){
                const int nb = buf^1;
                float* nA = sA + nb*KB*TILE_R;
                float* nB = sB + nb*KB*256;
                nA[(la_kk  )*TILE_R + la_row]=va.x; nA[(la_kk+1)*TILE_R + la_row]=va.y;
                nA[(la_kk+2)*TILE_R + la_row]=va.z; nA[(la_kk+3)*TILE_R + la_row]=va.w;
                #pragma unroll
                for (int i=0;i<4;++i) *(float4*)&nB[lb_kk*256 + lb_col + 4*i] = vb[i];
            }
            __syncthreads();
        }

        // pass epilogue: cols c0 + tx + 32c ; c<4 -> panel 2*p2 (d=tx+32c), c>=4 -> panel 2*p2+1
        float beC[8];
        #pragma unroll
        for (int c=0;c<8;++c) beC[c] = be2[c0 + tx + 32*c];
        const int pA_ = 2*p2, pB_ = 2*p2+1;
        #pragma unroll
        for (int r=0;r<8;++r){
            float e[8];
            #pragma unroll
            for (int c=0;c<8;++c) e[c] = acc[r][c] + beC[c];
            float pnA = 0.f, pnB = 0.f;
            #pragma unroll
            for (int c=0;c<4;++c){ pnA = fmaf(e[c], e[c], pnA); pnB = fmaf(e[c+4], e[c+4], pnB); }
            float psA[M_POP], psB[M_POP];
            #pragma unroll
            for (int jj=0;jj<M_POP;++jj){
                float s1=0.f, s2=0.f;
                #pragma unroll
                for (int c=0;c<4;++c){
                    float kv = sKn[jj*D_DIM + tx + 32*c];
                    s1 = fmaf(e[c],   kv, s1);
                    s2 = fmaf(e[c+4], kv, s2);
                }
                psA[jj]=s1; psB[jj]=s2;
            }
            #pragma unroll
            for (int mk=1; mk<=16; mk<<=1){
                pnA += __shfl_xor(pnA, mk, 64);
                pnB += __shfl_xor(pnB, mk, 64);
                #pragma unroll
                for (int jj=0;jj<M_POP;++jj){
                    psA[jj] += __shfl_xor(psA[jj], mk, 64);
                    psB[jj] += __shfl_xor(psB[jj], mk, 64);
                }
            }
            if (tx == 0){
                int rl = ty*8 + r;
                sNrm[rl*M_EMB + pA_] = pnA;
                sNrm[rl*M_EMB + pB_] = pnB;
                #pragma unroll
                for (int jj=0;jj<M_POP;++jj){
                    sSim[(rl*M_EMB + pA_)*M_POP + jj] = psA[jj];
                    sSim[(rl*M_EMB + pB_)*M_POP + jj] = psB[jj];
                }
            }
        }
        __syncthreads();   // sA/sB reuse next pass; sSim visibility
    }

    // ---- per-row finalize: sinkhorn + blend + action ----
    if (tid < TILE_R){
        const int grow = row0 + tid;
        float logK[M_EMB][M_POP];
        #pragma unroll
        for (int i=0;i<M_EMB;++i){
            float invn = 1.0f/(sqrtf(sNrm[tid*M_EMB + i]) + 1e-8f);
            #pragma unroll
            for (int jj=0;jj<M_POP;++jj){
                float sim = sSim[(tid*M_EMB + i)*M_POP + jj]*invn;
                float C = 1.0f - sim - 0.1f*dsimI[(size_t)grow*M_POP + jj];
                logK[i][jj] = -20.0f*C;
            }
        }
        const float LOG_MU = -1.7917594692280550f;   // -log(6)
        const float LOG_NU = -2.0794415416798357f;   // -log(8)
        float u[M_EMB], v[M_POP];
        #pragma unroll
        for (int i=0;i<M_EMB;++i) u[i]=0.f;
        #pragma unroll
        for (int jj=0;jj<M_POP;++jj) v[jj]=0.f;
        for (int it=0; it<10; ++it){
            #pragma unroll
            for (int i=0;i<M_EMB;++i){
                float mx = -1e30f;
                #pragma unroll
                for (int jj=0;jj<M_POP;++jj) mx = fmaxf(mx, logK[i][jj]+v[jj]);
                float s = 0.f;
                #pragma unroll
                for (int jj=0;jj<M_POP;++jj) s += __expf(logK[i][jj]+v[jj]-mx);
                u[i] = LOG_MU - (mx + __logf(s));
            }
            #pragma unroll
            for (int jj=0;jj<M_POP;++jj){
                float mx = -1e30f;
                #pragma unroll
                for (int i=0;i<M_EMB;++i) mx = fmaxf(mx, logK[i][jj]+u[i]);
                float s = 0.f;
                #pragma unroll
                for (int i=0;i<M_EMB;++i) s += __expf(logK[i][jj]+u[i]-mx);
                v[jj] = LOG_NU - (mx + __logf(s));
            }
        }
        float wot[M_POP]; float wsum = 0.f;
        #pragma unroll
        for (int jj=0;jj<M_POP;++jj){
            float s = 0.f;
            #pragma unroll
            for (int i=0;i<M_EMB;++i) s += __expf(logK[i][jj]+u[i]+v[jj]);
            wot[jj]=s; wsum += s;
        }
        float invw = 1.0f/(wsum + 1e-8f);
        float cl = crisL[grow];
        float eta = 0.05f + 0.15f*cl;
        float wrep[M_POP]; float rsum=0.f;
        #pragma unroll
        for (int jj=0;jj<M_POP;++jj){
            wrep[jj] = w_prev[jj]*__expf(eta*fitness[(size_t)grow*M_POP+jj]);
            rsum += wrep[jj];
        }
        float invr = 1.0f/(rsum + 1e-8f);
        float al = fminf(fmaxf(0.3f - 0.24f*cl, 0.06f), 0.3f);
        float w[M_POP]; float ws2=0.f;
        #pragma unroll
        for (int jj=0;jj<M_POP;++jj){
            w[jj] = (1.0f-al)*wrep[jj]*invr + al*wot[jj]*invw;
            ws2 += w[jj];
        }
        float invw2 = 1.0f/(ws2 + 1e-8f);
        #pragma unroll
        for (int jj=0;jj<M_POP;++jj) w[jj] *= invw2;
        float mc[A_DIM]; float mmax = -1e30f;
        #pragma unroll
        for (int a=0;a<A_DIM;++a){
            float s = 1.0f;
            #pragma unroll
            for (int jj=0;jj<M_POP;++jj) s = fmaf(w[jj], sConc[jj*A_DIM+a], s);
            mc[a]=s; mmax = fmaxf(mmax, s);
        }
        float es = 0.f;
        #pragma unroll
        for (int a=0;a<A_DIM;++a){ mc[a] = __expf(mc[a]-mmax); es += mc[a]; }
        float inve = 1.0f/es;
        float s3 = 0.f;
        #pragma unroll
        for (int a=0;a<A_DIM;++a){ mc[a] *= inve; s3 += mc[a]; }
        float invf = 1.0f/(s3 + 1e-8f);
        #pragma unroll
        for (int a=0;a<A_DIM;++a) sAct[tid*A_DIM + a] = mc[a]*invf;
    }
    __syncthreads();
    for (int q = tid; q < TILE_R*A_DIM; q += 256)
        out[(size_t)row0*A_DIM + q] = sAct[q];
}

extern "C" void kernel_launch(void* const* d_in, const int* in_sizes, int n_in,
                              void* d_out, int out_size, void* d_ws, size_t ws_size,
                              hipStream_t stream)
{
    const float* state       = (const float*)d_in[0];
    const float* fitness     = (const float*)d_in[1];
    const float* we1         = (const float*)d_in[2];
    const float* be1         = (const float*)d_in[3];
    const float* lng         = (const float*)d_in[4];
    const float* lnb         = (const float*)d_in[5];
    const float* we2         = (const float*)d_in[6];
    const float* be2         = (const float*)d_in[7];
    const float* proto       = (const float*)d_in[8];
    const float* wd1         = (const float*)d_in[9];
    const float* bd1         = (const float*)d_in[10];
    const float* wd2         = (const float*)d_in[11];
    const float* bd2         = (const float*)d_in[12];
    const float* wt          = (const float*)d_in[13];
    const float* bt          = (const float*)d_in[14];
    // d_in[15]=wz, d_in[16]=bz are dead code in the reference (z unused)
    const float* wc          = (const float*)d_in[17];
    const float* bc          = (const float*)d_in[18];
    const float* w_prev      = (const float*)d_in[19];
    const float* crisis_bias = (const float*)d_in[20];

    float* ws    = (float*)d_ws;
    float* h1    = ws;                                   // B*256
    float* crisL = h1    + (size_t)B_TOT*H1_DIM;         // B
    float* dsim  = crisL + B_TOT;                        // B*8
    float* Kn    = dsim  + (size_t)B_TOT*M_POP;          // 1024
    float* conc  = Kn    + M_POP*D_DIM;                  // 240
    float* outp  = (float*)d_out;

    k0_precompute<<<1, 256, 0, stream>>>(proto, wd1, bd1, wd2, bd2, Kn, conc);
    k1_h1_aux<<<B_TOT/TILE_R, 256, 0, stream>>>(state, we1, be1, lng, lnb,
                                                wt, bt, wc, bc, crisis_bias, Kn,
                                                h1, crisL, dsim);
    k2_emb_sink_out<<<B_TOT/TILE_R, 256, 0, stream>>>(h1, we2, be2, Kn, conc,
                                                      crisL, dsim, fitness, w_prev, outp);
}

// Round 4
// 779.029 us; speedup vs baseline: 2.9841x; 2.9841x over previous
//
#include <hip/hip_runtime.h>
#include <math.h>

#define B_TOT   131072
#define S_DIM   274
#define H1_DIM  256
#define M_EMB   6
#define M_POP   8
#define D_DIM   128
#define A_DIM   30

typedef __attribute__((ext_vector_type(8))) short bf16x8;
typedef __attribute__((ext_vector_type(4))) float f32x4;

__device__ __forceinline__ float sigmf(float x){ return 1.0f/(1.0f+__expf(-x)); }

__device__ __forceinline__ unsigned short f2bf(float f){
    union { float f; unsigned int u; } v; v.f = f;
    unsigned int r = v.u + 0x7FFFu + ((v.u >> 16) & 1u);
    return (unsigned short)(r >> 16);
}

__device__ __forceinline__ bf16x8 pack8(const float* v){
    bf16x8 r;
    #pragma unroll
    for (int j=0;j<8;++j) r[j] = (short)f2bf(v[j]);
    return r;
}

// ============ k0a: Kn, conc, W2K, bK (single block) ============
__global__ void k0a_precompute(const float* __restrict__ proto,
                               const float* __restrict__ wd1, const float* __restrict__ bd1,
                               const float* __restrict__ wd2, const float* __restrict__ bd2,
                               const float* __restrict__ we2, const float* __restrict__ be2,
                               float* __restrict__ Kn, float* __restrict__ conc,
                               float* __restrict__ W2K, float* __restrict__ bK)
{
    __shared__ float sKn[M_POP][D_DIM];
    __shared__ float sHd[M_POP][D_DIM];
    const int t = threadIdx.x;
    const int j = t >> 5, lane32 = t & 31;
    // Kn
    float ss = 0.f;
    for (int q = lane32; q < D_DIM; q += 32){ float v = proto[j*D_DIM+q]; ss += v*v; }
    #pragma unroll
    for (int mk = 16; mk >= 1; mk >>= 1) ss += __shfl_xor(ss, mk, 64);
    float inv = 1.0f / (sqrtf(ss) + 1e-8f);
    for (int q = lane32; q < D_DIM; q += 32){
        float kv = proto[j*D_DIM+q]*inv;
        Kn[j*D_DIM+q] = kv; sKn[j][q] = kv;
    }
    // hd for conc
    for (int h = lane32; h < D_DIM; h += 32){
        float acc = bd1[j*D_DIM+h];
        for (int d = 0; d < D_DIM; ++d)
            acc = fmaf(proto[j*D_DIM+d], wd1[(j*D_DIM+d)*D_DIM + h], acc);
        sHd[j][h] = fmaxf(acc, 0.f);
    }
    __syncthreads();
    // conc
    if (t < M_POP*A_DIM){
        int jj = t / A_DIM, a = t - jj*A_DIM;
        float acc = bd2[jj*A_DIM + a];
        for (int h = 0; h < D_DIM; ++h)
            acc = fmaf(sHd[jj][h], wd2[(jj*D_DIM+h)*A_DIM + a], acc);
        float sp;
        if (acc > 20.f)       sp = acc;
        else if (acc < -20.f) sp = expf(acc);
        else                  sp = log1pf(expf(acc));
        conc[jj*A_DIM + a] = sp;
    }
    // W2K[k][pc] = sum_d we2[k][(pc>>3)*128+d] * Kn[pc&7][d]
    for (int o = t; o < 256*48; o += 256){
        int k = o / 48, pc = o - k*48;
        int jj = pc & 7, col0 = (pc >> 3) * 128;
        const float4* wrow = (const float4*)(we2 + (size_t)k*768 + col0);
        const float4* krow = (const float4*)(&sKn[jj][0]);
        float4 s4 = make_float4(0.f,0.f,0.f,0.f);
        #pragma unroll 8
        for (int dq = 0; dq < 32; ++dq){
            float4 wv = wrow[dq], kv = krow[dq];
            s4.x = fmaf(wv.x,kv.x,s4.x); s4.y = fmaf(wv.y,kv.y,s4.y);
            s4.z = fmaf(wv.z,kv.z,s4.z); s4.w = fmaf(wv.w,kv.w,s4.w);
        }
        W2K[o] = (s4.x+s4.y)+(s4.z+s4.w);
    }
    // bK
    if (t < 48){
        int jj = t & 7, col0 = (t >> 3) * 128;
        const float4* brow = (const float4*)(be2 + col0);
        const float4* krow = (const float4*)(&sKn[jj][0]);
        float4 s4 = make_float4(0.f,0.f,0.f,0.f);
        #pragma unroll 8
        for (int dq = 0; dq < 32; ++dq){
            float4 bv = brow[dq], kv = krow[dq];
            s4.x = fmaf(bv.x,kv.x,s4.x); s4.y = fmaf(bv.y,kv.y,s4.y);
            s4.z = fmaf(bv.z,kv.z,s4.z); s4.w = fmaf(bv.w,kv.w,s4.w);
        }
        bK[t] = (s4.x+s4.y)+(s4.z+s4.w);
    }
}

// ============ k0b: we1 -> B1 frag layout (K padded 274->288, 9 ksteps, 16 ct) ============
// slot s = (ct*9+ks)*64 + lam ; elem j: k = 32ks + (lam>>4)*8 + j, col = 16ct + (lam&15)
__global__ void k0b_we1_frag(const float* __restrict__ we1, short* __restrict__ B1f)
{
    int s = blockIdx.x*256 + threadIdx.x;      // < 9216
    int ct = s / (9*64);
    int rem = s - ct*(9*64);
    int ks = rem >> 6, lam = rem & 63;
    int kb = 32*ks + (lam>>4)*8;
    int col = 16*ct + (lam&15);
    float v[8];
    #pragma unroll
    for (int j=0;j<8;++j){
        int k = kb + j;
        v[j] = (k < S_DIM) ? we1[(size_t)k*H1_DIM + col] : 0.f;
    }
    bf16x8 p = pack8(v);
    *(bf16x8*)(B1f + (size_t)s*8) = p;
}

// ============ k0c: [we2 | W2K] -> B2 frag layout (816 cols = 51 ct, 8 ksteps) ============
__global__ void k0c_we2_frag(const float* __restrict__ we2, const float* __restrict__ W2K,
                             short* __restrict__ B2f)
{
    int s = blockIdx.x*256 + threadIdx.x;      // < 26112
    int ct = s / (8*64);
    int rem = s - ct*(8*64);
    int ks = rem >> 6, lam = rem & 63;
    int kb = 32*ks + (lam>>4)*8;
    int col = 16*ct + (lam&15);
    float v[8];
    #pragma unroll
    for (int j=0;j<8;++j){
        int k = kb + j;
        v[j] = (col < 768) ? we2[(size_t)k*768 + col] : W2K[k*48 + (col-768)];
    }
    bf16x8 p = pack8(v);
    *(bf16x8*)(B2f + (size_t)s*8) = p;
}

// ============ k1: MFMA GEMM1 + LN + relu -> h1 bf16 ; aux crisis/dsim ============
// block = 128 rows, 4 waves, wave tile 32 rows (2 rt) x 256 cols (16 ct), K = 288 (9 ksteps)
__global__ __launch_bounds__(256, 2)
void k1_h1_aux(const float* __restrict__ state, const short* __restrict__ B1f,
               const float* __restrict__ be1, const float* __restrict__ lng,
               const float* __restrict__ lnb, const float* __restrict__ wt,
               const float* __restrict__ bt,  const float* __restrict__ wc,
               const float* __restrict__ bc,  const float* __restrict__ crisis_bias,
               const float* __restrict__ Kn,
               short* __restrict__ h1b, float* __restrict__ crisL, float* __restrict__ dsimO)
{
    __shared__ short ldsB[2][8192];            // 2 x 16KB k-chunks (frag order)
    const int tid  = threadIdx.x;
    const int lane = tid & 63, w = tid >> 6;
    const int grp  = lane >> 4;
    const int row0 = blockIdx.x * 128;

    // ---------- aux: crisis + dsim (2 threads/row) ----------
    {
        const int r = tid >> 1, part = tid & 1;
        const float* srow = state + (size_t)(row0 + r) * S_DIM;
        float bal = srow[0];
        float sp = 0.f;
        for (int q = 1; q <= 30; ++q) sp += srow[q];
        float pmean = sp * (1.0f/30.0f);
        float sv = 0.f, tv = bal;
        for (int q = 1; q <= 30; ++q){
            float p = srow[q];
            float d = p - pmean; sv = fmaf(d,d,sv);
            tv = fmaf(p, srow[q+30], tv);
        }
        float pstd = sqrtf(sv * (1.0f/29.0f)) + 1e-8f;
        float cash = bal / (tv + 1e-8f);
        float mf[12];
        mf[0]=bal; mf[1]=pmean; mf[2]=pstd; mf[3]=cash;
        mf[4]=srow[61];  mf[5]=srow[91];   mf[6]=srow[121]; mf[7]=srow[151];
        mf[8]=srow[181]; mf[9]=srow[211];  mf[10]=srow[241]; mf[11]=srow[271];
        float csum=0.f, nsum=0.f;
        float ssum[M_POP];
        #pragma unroll
        for (int jj=0;jj<M_POP;++jj) ssum[jj]=0.f;
        const float4* wt4 = (const float4*)wt;
        const float4* bt4 = (const float4*)bt;
        const float4* wc4 = (const float4*)wc;
        const float4* Kn4 = (const float4*)Kn;
        for (int dq = 0; dq < 16; ++dq){
            int qi = part*16 + dq;
            float4 a = bt4[qi];
            #pragma unroll
            for (int f = 0; f < 12; ++f){
                float4 wv = wt4[f*32 + qi];
                a.x = fmaf(mf[f],wv.x,a.x); a.y = fmaf(mf[f],wv.y,a.y);
                a.z = fmaf(mf[f],wv.z,a.z); a.w = fmaf(mf[f],wv.w,a.w);
            }
            a.x=fmaxf(a.x,0.f); a.y=fmaxf(a.y,0.f); a.z=fmaxf(a.z,0.f); a.w=fmaxf(a.w,0.f);
            float4 cv = wc4[qi];
            csum += a.x*cv.x + a.y*cv.y + a.z*cv.z + a.w*cv.w;
            nsum += a.x*a.x + a.y*a.y + a.z*a.z + a.w*a.w;
            #pragma unroll
            for (int jj=0;jj<M_POP;++jj){
                float4 kv = Kn4[jj*32 + qi];
                ssum[jj] += a.x*kv.x + a.y*kv.y + a.z*kv.z + a.w*kv.w;
            }
        }
        csum += __shfl_xor(csum, 1, 64);
        nsum += __shfl_xor(nsum, 1, 64);
        #pragma unroll
        for (int jj=0;jj<M_POP;++jj) ssum[jj] += __shfl_xor(ssum[jj], 1, 64);
        if (part == 0){
            float cb  = sigmf(csum + bc[0]);
            float dss = sigmf(srow[272]*10.0f);
            float cvs = sigmf(fabsf(srow[273])*50.0f);
            crisL[row0+r] = 0.6f*cb + 0.25f*dss + 0.15f*cvs + crisis_bias[0];
            float invd = 1.0f/(sqrtf(nsum) + 1e-8f);
            #pragma unroll
            for (int jj=0;jj<M_POP;++jj) dsimO[(size_t)(row0+r)*M_POP + jj] = ssum[jj]*invd;
        }
    }

    // ---------- A fragments from state (fp32 -> bf16), K padded to 288 ----------
    bf16x8 Af[2][9];
    #pragma unroll
    for (int rt=0;rt<2;++rt){
        int row = row0 + w*32 + rt*16 + (lane&15);
        const float* sp = state + (size_t)row*S_DIM;
        #pragma unroll
        for (int ks=0;ks<9;++ks){
            float v[8];
            int kb = 32*ks + grp*8;
            if (ks < 8){
                #pragma unroll
                for (int h=0;h<4;++h){
                    float2 t2 = *(const float2*)(sp + kb + 2*h);
                    v[2*h] = t2.x; v[2*h+1] = t2.y;
                }
            } else {
                #pragma unroll
                for (int j2=0;j2<8;++j2) v[j2]=0.f;
                if (grp < 2){
                    #pragma unroll
                    for (int h=0;h<4;++h){
                        float2 t2 = *(const float2*)(sp + kb + 2*h);
                        v[2*h] = t2.x; v[2*h+1] = t2.y;
                    }
                } else if (grp == 2){
                    float2 t2 = *(const float2*)(sp + 272);
                    v[0] = t2.x; v[1] = t2.y;
                }
            }
            Af[rt][ks] = pack8(v);
        }
    }

    // ---------- GEMM main loop ----------
    f32x4 acc[2][16];
    #pragma unroll
    for (int rt=0;rt<2;++rt)
        #pragma unroll
        for (int ct=0;ct<16;++ct) acc[rt][ct] = (f32x4){0.f,0.f,0.f,0.f};

    float4 vr[4];
    #pragma unroll
    for (int i=0;i<4;++i){
        int slot = i*256 + tid; int ctl = slot>>6, lam = slot&63;
        vr[i] = *(const float4*)(B1f + ((size_t)(ctl*9 + 0)*64 + lam)*8);
    }
    #pragma unroll
    for (int i=0;i<4;++i){
        int slot = i*256 + tid; int ctl = slot>>6, lam = slot&63;
        *(float4*)&ldsB[0][ctl*512 + lam*8] = vr[i];
    }
    __syncthreads();
    #pragma unroll
    for (int ks=0; ks<9; ++ks){
        if (ks < 8){
            #pragma unroll
            for (int i=0;i<4;++i){
                int slot = i*256 + tid; int ctl = slot>>6, lam = slot&63;
                vr[i] = *(const float4*)(B1f + ((size_t)(ctl*9 + ks+1)*64 + lam)*8);
            }
        }
        const int bo = (ks&1)*8192;
        #pragma unroll
        for (int ct=0; ct<16; ++ct){
            bf16x8 bf = *(const bf16x8*)&ldsB[0][bo + ct*512 + lane*8];
            acc[0][ct] = __builtin_amdgcn_mfma_f32_16x16x32_bf16(Af[0][ks], bf, acc[0][ct], 0,0,0);
            acc[1][ct] = __builtin_amdgcn_mfma_f32_16x16x32_bf16(Af[1][ks], bf, acc[1][ct], 0,0,0);
        }
        if (ks < 8){
            const int bo2 = ((ks+1)&1)*8192;
            #pragma unroll
            for (int i=0;i<4;++i){
                int slot = i*256 + tid; int ctl = slot>>6, lam = slot&63;
                *(float4*)&ldsB[0][bo2 + ctl*512 + lam*8] = vr[i];
            }
        }
        __syncthreads();
    }

    // ---------- bias + LN + relu -> bf16 h1 (via per-wave LDS transpose) ----------
    short* eLds = (short*)ldsB;                 // 4 wave regions of 8KB (16 rows x 256 cols bf16)
    const int wbase = w * 4096;
    #pragma unroll
    for (int rt=0;rt<2;++rt){
        float s[4] = {0.f,0.f,0.f,0.f};
        float sq[4] = {0.f,0.f,0.f,0.f};
        #pragma unroll
        for (int ct=0;ct<16;++ct){
            float be = be1[ct*16 + (lane&15)];
            #pragma unroll
            for (int r=0;r<4;++r){
                float h = acc[rt][ct][r] + be;
                acc[rt][ct][r] = h;
                s[r] += h; sq[r] = fmaf(h,h,sq[r]);
            }
        }
        #pragma unroll
        for (int mk=1; mk<=8; mk<<=1){
            #pragma unroll
            for (int r=0;r<4;++r){ s[r] += __shfl_xor(s[r],mk,64); sq[r] += __shfl_xor(sq[r],mk,64); }
        }
        float rstd[4], mu[4];
        #pragma unroll
        for (int r=0;r<4;++r){
            mu[r] = s[r] * (1.0f/256.0f);
            float var = sq[r]*(1.0f/256.0f) - mu[r]*mu[r];
            rstd[r] = rsqrtf(var + 1e-5f);
        }
        #pragma unroll
        for (int ct=0;ct<16;++ct){
            int col = ct*16 + (lane&15);
            float g = lng[col], bb = lnb[col];
            #pragma unroll
            for (int r=0;r<4;++r){
                float v = (acc[rt][ct][r]-mu[r])*rstd[r]*g + bb;
                v = fmaxf(v, 0.f);
                eLds[wbase + ((grp*4)+r)*256 + col] = (short)f2bf(v);
            }
        }
        // copy out 16 rows (8KB) coalesced
        int rowStart = row0 + w*32 + rt*16;
        #pragma unroll
        for (int i=0;i<8;++i){
            float4 d4 = *(const float4*)&eLds[wbase + (i*64 + lane)*8];
            *(float4*)(h1b + (size_t)rowStart*256 + (i*64+lane)*8) = d4;
        }
    }
}

// ============ k2: MFMA GEMM2 (768 E cols + 48 sim cols) + sinkhorn + action ============
template<int NCT>
__device__ __forceinline__ void k2_gemm_pass(f32x4 (&acc)[2][16], const bf16x8 (&Af)[2][8],
        short* ldsB, const short* __restrict__ B2f, int pass, int tid, int lane)
{
    #pragma unroll
    for (int rt=0;rt<2;++rt)
        #pragma unroll
        for (int ct=0;ct<NCT;++ct) acc[rt][ct] = (f32x4){0.f,0.f,0.f,0.f};
    float4 vr[4];
    #pragma unroll
    for (int i=0;i<4;++i){
        int slot = i*256 + tid;
        if (slot < NCT*64){ int ctl = slot>>6, lam = slot&63;
            vr[i] = *(const float4*)(B2f + ((size_t)((pass*16+ctl)*8 + 0)*64 + lam)*8); }
    }
    #pragma unroll
    for (int i=0;i<4;++i){
        int slot = i*256 + tid;
        if (slot < NCT*64){ int ctl = slot>>6, lam = slot&63;
            *(float4*)&ldsB[ctl*512 + lam*8] = vr[i]; }
    }
    __syncthreads();
    #pragma unroll
    for (int ks=0; ks<8; ++ks){
        if (ks < 7){
            #pragma unroll
            for (int i=0;i<4;++i){
                int slot = i*256 + tid;
                if (slot < NCT*64){ int ctl = slot>>6, lam = slot&63;
                    vr[i] = *(const float4*)(B2f + ((size_t)((pass*16+ctl)*8 + ks+1)*64 + lam)*8); }
            }
        }
        const int bo = (ks&1)*8192;
        #pragma unroll
        for (int ct=0; ct<NCT; ++ct){
            bf16x8 bf = *(const bf16x8*)&ldsB[bo + ct*512 + lane*8];
            acc[0][ct] = __builtin_amdgcn_mfma_f32_16x16x32_bf16(Af[0][ks], bf, acc[0][ct], 0,0,0);
            acc[1][ct] = __builtin_amdgcn_mfma_f32_16x16x32_bf16(Af[1][ks], bf, acc[1][ct], 0,0,0);
        }
        if (ks < 7){
            const int bo2 = ((ks+1)&1)*8192;
            #pragma unroll
            for (int i=0;i<4;++i){
                int slot = i*256 + tid;
                if (slot < NCT*64){ int ctl = slot>>6, lam = slot&63;
                    *(float4*)&ldsB[bo2 + ctl*512 + lam*8] = vr[i]; }
            }
        }
        __syncthreads();
    }
}

__global__ __launch_bounds__(256, 2)
void k2_emb_sink_out(const short* __restrict__ h1b, const short* __restrict__ B2f,
                     const float* __restrict__ be2, const float* __restrict__ bK,
                     const float* __restrict__ conc, const float* __restrict__ crisL,
                     const float* __restrict__ dsimI, const float* __restrict__ fitness,
                     const float* __restrict__ w_prev, float* __restrict__ out)
{
    __shared__ short ldsB[2][8192];            // 32KB staging (reused as sAct)
    __shared__ float sNrm[128*9];
    __shared__ float sSim[128*49];
    __shared__ float sConc[M_POP*A_DIM];
    const int tid  = threadIdx.x;
    const int lane = tid & 63, w = tid >> 6;
    const int grp  = lane >> 4;
    const int row0 = blockIdx.x * 128;

    for (int q = tid; q < M_POP*A_DIM; q += 256) sConc[q] = conc[q];

    // A fragments from bf16 h1 (registers, reused across all passes)
    bf16x8 Af[2][8];
    #pragma unroll
    for (int rt=0;rt<2;++rt){
        int row = row0 + w*32 + rt*16 + (lane&15);
        #pragma unroll
        for (int ks=0;ks<8;++ks)
            Af[rt][ks] = *(const bf16x8*)(h1b + (size_t)row*256 + 32*ks + grp*8);
    }

    f32x4 acc[2][16];
    // ---- 3 E passes: accumulate per-panel normsq only ----
    #pragma unroll 1
    for (int pass=0; pass<3; ++pass){
        k2_gemm_pass<16>(acc, Af, &ldsB[0][0], B2f, pass, tid, lane);
        float nsq[2][4][2];
        #pragma unroll
        for (int rt=0;rt<2;++rt)
            #pragma unroll
            for (int r=0;r<4;++r){ nsq[rt][r][0]=0.f; nsq[rt][r][1]=0.f; }
        #pragma unroll
        for (int ct=0;ct<16;++ct){
            float be = be2[pass*256 + ct*16 + (lane&15)];
            const int hh = ct >> 3;
            #pragma unroll
            for (int rt=0;rt<2;++rt)
                #pragma unroll
                for (int r=0;r<4;++r){
                    float e = acc[rt][ct][r] + be;
                    nsq[rt][r][hh] = fmaf(e,e,nsq[rt][r][hh]);
                }
        }
        #pragma unroll
        for (int mk=1; mk<=8; mk<<=1){
            #pragma unroll
            for (int rt=0;rt<2;++rt)
                #pragma unroll
                for (int r=0;r<4;++r){
                    nsq[rt][r][0] += __shfl_xor(nsq[rt][r][0],mk,64);
                    nsq[rt][r][1] += __shfl_xor(nsq[rt][r][1],mk,64);
                }
        }
        if ((lane&15) < 2){
            int panel = 2*pass + (lane&15);
            #pragma unroll
            for (int rt=0;rt<2;++rt)
                #pragma unroll
                for (int r=0;r<4;++r){
                    int row = w*32 + rt*16 + grp*4 + r;
                    sNrm[row*9 + panel] = nsq[rt][r][lane&15];
                }
        }
        __syncthreads();   // before ldsB reuse next pass
    }
    // ---- sim pass (48 folded cols) ----
    k2_gemm_pass<3>(acc, Af, &ldsB[0][0], B2f, 3, tid, lane);
    #pragma unroll
    for (int ct=0;ct<3;++ct){
        float bKv = bK[ct*16 + (lane&15)];
        #pragma unroll
        for (int rt=0;rt<2;++rt)
            #pragma unroll
            for (int r=0;r<4;++r){
                int row = w*32 + rt*16 + grp*4 + r;
                sSim[row*49 + ct*16 + (lane&15)] = acc[rt][ct][r] + bKv;
            }
    }
    __syncthreads();

    // ---- per-row sinkhorn + blend + action ----
    float* sAct = (float*)ldsB;
    if (tid < 128){
        const int grow = row0 + tid;
        float invn[M_EMB];
        #pragma unroll
        for (int i=0;i<M_EMB;++i) invn[i] = 1.0f/(sqrtf(sNrm[tid*9+i]) + 1e-8f);
        float logK[M_EMB][M_POP];
        #pragma unroll
        for (int i=0;i<M_EMB;++i){
            #pragma unroll
            for (int jj=0;jj<M_POP;++jj){
                float sim = sSim[tid*49 + i*8 + jj]*invn[i];
                float C = 1.0f - sim - 0.1f*dsimI[(size_t)grow*M_POP + jj];
                logK[i][jj] = -20.0f*C;
            }
        }
        const float LOG_MU = -1.7917594692280550f;
        const float LOG_NU = -2.0794415416798357f;
        float u[M_EMB], v[M_POP];
        #pragma unroll
        for (int i=0;i<M_EMB;++i) u[i]=0.f;
        #pragma unroll
        for (int jj=0;jj<M_POP;++jj) v[jj]=0.f;
        for (int it=0; it<10; ++it){
            #pragma unroll
            for (int i=0;i<M_EMB;++i){
                float mx = -1e30f;
                #pragma unroll
                for (int jj=0;jj<M_POP;++jj) mx = fmaxf(mx, logK[i][jj]+v[jj]);
                float sum = 0.f;
                #pragma unroll
                for (int jj=0;jj<M_POP;++jj) sum += __expf(logK[i][jj]+v[jj]-mx);
                u[i] = LOG_MU - (mx + __logf(sum));
            }
            #pragma unroll
            for (int jj=0;jj<M_POP;++jj){
                float mx = -1e30f;
                #pragma unroll
                for (int i=0;i<M_EMB;++i) mx = fmaxf(mx, logK[i][jj]+u[i]);
                float sum = 0.f;
                #pragma unroll
                for (int i=0;i<M_EMB;++i) sum += __expf(logK[i][jj]+u[i]-mx);
                v[jj] = LOG_NU - (mx + __logf(sum));
            }
        }
        float wot[M_POP]; float wsum = 0.f;
        #pragma unroll
        for (int jj=0;jj<M_POP;++jj){
            float sum = 0.f;
            #pragma unroll
            for (int i=0;i<M_EMB;++i) sum += __expf(logK[i][jj]+u[i]+v[jj]);
            wot[jj]=sum; wsum += sum;
        }
        float invw = 1.0f/(wsum + 1e-8f);
        float cl = crisL[grow];
        float eta = 0.05f + 0.15f*cl;
        float wrep[M_POP]; float rsum=0.f;
        #pragma unroll
        for (int jj=0;jj<M_POP;++jj){
            wrep[jj] = w_prev[jj]*__expf(eta*fitness[(size_t)grow*M_POP+jj]);
            rsum += wrep[jj];
        }
        float invr = 1.0f/(rsum + 1e-8f);
        float al = fminf(fmaxf(0.3f - 0.24f*cl, 0.06f), 0.3f);
        float wv[M_POP]; float ws2=0.f;
        #pragma unroll
        for (int jj=0;jj<M_POP;++jj){
            wv[jj] = (1.0f-al)*wrep[jj]*invr + al*wot[jj]*invw;
            ws2 += wv[jj];
        }
        float invw2 = 1.0f/(ws2 + 1e-8f);
        #pragma unroll
        for (int jj=0;jj<M_POP;++jj) wv[jj] *= invw2;
        float mc[A_DIM]; float mmax = -1e30f;
        #pragma unroll
        for (int a=0;a<A_DIM;++a){
            float sum = 1.0f;
            #pragma unroll
            for (int jj=0;jj<M_POP;++jj) sum = fmaf(wv[jj], sConc[jj*A_DIM+a], sum);
            mc[a]=sum; mmax = fmaxf(mmax, sum);
        }
        float es = 0.f;
        #pragma unroll
        for (int a=0;a<A_DIM;++a){ mc[a] = __expf(mc[a]-mmax); es += mc[a]; }
        float inve = 1.0f/es;
        float s3 = 0.f;
        #pragma unroll
        for (int a=0;a<A_DIM;++a){ mc[a] *= inve; s3 += mc[a]; }
        float invf = 1.0f/(s3 + 1e-8f);
        #pragma unroll
        for (int a=0;a<A_DIM;++a) sAct[tid*A_DIM + a] = mc[a]*invf;
    }
    __syncthreads();
    for (int q = tid; q < 128*A_DIM; q += 256)
        out[(size_t)row0*A_DIM + q] = sAct[q];
}

extern "C" void kernel_launch(void* const* d_in, const int* in_sizes, int n_in,
                              void* d_out, int out_size, void* d_ws, size_t ws_size,
                              hipStream_t stream)
{
    const float* state       = (const float*)d_in[0];
    const float* fitness     = (const float*)d_in[1];
    const float* we1         = (const float*)d_in[2];
    const float* be1         = (const float*)d_in[3];
    const float* lng         = (const float*)d_in[4];
    const float* lnb         = (const float*)d_in[5];
    const float* we2         = (const float*)d_in[6];
    const float* be2         = (const float*)d_in[7];
    const float* proto       = (const float*)d_in[8];
    const float* wd1         = (const float*)d_in[9];
    const float* bd1         = (const float*)d_in[10];
    const float* wd2         = (const float*)d_in[11];
    const float* bd2         = (const float*)d_in[12];
    const float* wt          = (const float*)d_in[13];
    const float* bt          = (const float*)d_in[14];
    // d_in[15]=wz, d_in[16]=bz dead code
    const float* wc          = (const float*)d_in[17];
    const float* bc          = (const float*)d_in[18];
    const float* w_prev      = (const float*)d_in[19];
    const float* crisis_bias = (const float*)d_in[20];

    float* ws = (float*)d_ws;
    short* h1b   = (short*)ws;                                  // bf16 [B][256] = B*128 floats
    float* crisL = ws + (size_t)B_TOT*128;                      // B
    float* dsim  = crisL + B_TOT;                               // B*8
    float* Kn    = dsim + (size_t)B_TOT*8;                      // 1024
    float* conc  = Kn + 1024;                                   // 240 (+16)
    float* W2K   = conc + 256;                                  // 12288
    float* bK    = W2K + 12288;                                 // 48 (+16)
    short* B1f   = (short*)(bK + 64);                           // 73728 bf16 = 36864 floats
    short* B2f   = (short*)(bK + 64 + 36864);                   // 208896 bf16
    float* outp  = (float*)d_out;

    k0a_precompute<<<1, 256, 0, stream>>>(proto, wd1, bd1, wd2, bd2, we2, be2,
                                          Kn, conc, W2K, bK);
    k0b_we1_frag<<<36, 256, 0, stream>>>(we1, B1f);
    k0c_we2_frag<<<102, 256, 0, stream>>>(we2, W2K, B2f);
    k1_h1_aux<<<B_TOT/128, 256, 0, stream>>>(state, B1f, be1, lng, lnb,
                                             wt, bt, wc, bc, crisis_bias, Kn,
                                             h1b, crisL, dsim);
    k2_emb_sink_out<<<B_TOT/128, 256, 0, stream>>>(h1b, B2f, be2, bK, conc,
                                                   crisL, dsim, fitness, w_prev, outp);
}

// Round 5
// 743.287 us; speedup vs baseline: 3.1276x; 1.0481x over previous
//
#include <hip/hip_runtime.h>
#include <math.h>

#define B_TOT   131072
#define S_DIM   274
#define H1_DIM  256
#define M_EMB   6
#define M_POP   8
#define D_DIM   128
#define A_DIM   30

typedef __attribute__((ext_vector_type(8))) short bf16x8;
typedef __attribute__((ext_vector_type(4))) float f32x4;

__device__ __forceinline__ float sigmf(float x){ return 1.0f/(1.0f+__expf(-x)); }

__device__ __forceinline__ unsigned short f2bf(float f){
    union { float f; unsigned int u; } v; v.f = f;
    unsigned int r = v.u + 0x7FFFu + ((v.u >> 16) & 1u);
    return (unsigned short)(r >> 16);
}

__device__ __forceinline__ bf16x8 pack8(const float* v){
    bf16x8 r;
    #pragma unroll
    for (int j=0;j<8;++j) r[j] = (short)f2bf(v[j]);
    return r;
}

// ============ k0a: Kn only (1 block) ============
__global__ void k0a_kn(const float* __restrict__ proto, float* __restrict__ Kn)
{
    const int t = threadIdx.x;
    const int j = t >> 5, lane32 = t & 31;
    float ss = 0.f;
    for (int q = lane32; q < D_DIM; q += 32){ float v = proto[j*D_DIM+q]; ss += v*v; }
    #pragma unroll
    for (int mk = 16; mk >= 1; mk >>= 1) ss += __shfl_xor(ss, mk, 64);
    float inv = 1.0f / (sqrtf(ss) + 1e-8f);
    for (int q = lane32; q < D_DIM; q += 32) Kn[j*D_DIM+q] = proto[j*D_DIM+q]*inv;
}

// ============ k0h: conc (8 blocks, one per j) ============
__global__ void k0h_conc(const float* __restrict__ proto,
                         const float* __restrict__ wd1, const float* __restrict__ bd1,
                         const float* __restrict__ wd2, const float* __restrict__ bd2,
                         float* __restrict__ conc)
{
    __shared__ float sHd[D_DIM];
    const int j = blockIdx.x;
    const int t = threadIdx.x;
    if (t < D_DIM){
        float acc = bd1[j*D_DIM + t];
        for (int d = 0; d < D_DIM; ++d)
            acc = fmaf(proto[j*D_DIM+d], wd1[(j*D_DIM+d)*D_DIM + t], acc);
        sHd[t] = fmaxf(acc, 0.f);
    }
    __syncthreads();
    if (t < A_DIM){
        float acc = bd2[j*A_DIM + t];
        for (int h = 0; h < D_DIM; ++h)
            acc = fmaf(sHd[h], wd2[(j*D_DIM+h)*A_DIM + t], acc);
        float sp;
        if (acc > 20.f)       sp = acc;
        else if (acc < -20.f) sp = expf(acc);
        else                  sp = log1pf(expf(acc));
        conc[j*A_DIM + t] = sp;
    }
}

// ============ k0w: W2K (blocks 0..47) + bK (block 48) ============
__global__ void k0w_w2k(const float* __restrict__ we2, const float* __restrict__ be2,
                        const float* __restrict__ Kn,
                        float* __restrict__ W2K, float* __restrict__ bK)
{
    const int t = threadIdx.x;
    if (blockIdx.x < 48){
        int o = blockIdx.x*256 + t;            // < 12288
        int k = o / 48, pc = o - k*48;
        int jj = pc & 7, col0 = (pc >> 3) * 128;
        const float4* wrow = (const float4*)(we2 + (size_t)k*768 + col0);
        const float4* krow = (const float4*)(Kn + jj*D_DIM);
        float4 s4 = make_float4(0.f,0.f,0.f,0.f);
        #pragma unroll 8
        for (int dq = 0; dq < 32; ++dq){
            float4 wv = wrow[dq], kv = krow[dq];
            s4.x = fmaf(wv.x,kv.x,s4.x); s4.y = fmaf(wv.y,kv.y,s4.y);
            s4.z = fmaf(wv.z,kv.z,s4.z); s4.w = fmaf(wv.w,kv.w,s4.w);
        }
        W2K[o] = (s4.x+s4.y)+(s4.z+s4.w);
    } else if (t < 48){
        int jj = t & 7, col0 = (t >> 3) * 128;
        const float4* brow = (const float4*)(be2 + col0);
        const float4* krow = (const float4*)(Kn + jj*D_DIM);
        float4 s4 = make_float4(0.f,0.f,0.f,0.f);
        #pragma unroll 8
        for (int dq = 0; dq < 32; ++dq){
            float4 bv = brow[dq], kv = krow[dq];
            s4.x = fmaf(bv.x,kv.x,s4.x); s4.y = fmaf(bv.y,kv.y,s4.y);
            s4.z = fmaf(bv.z,kv.z,s4.z); s4.w = fmaf(bv.w,kv.w,s4.w);
        }
        bK[t] = (s4.x+s4.y)+(s4.z+s4.w);
    }
}

// ============ k0b: we1 -> B1 frag layout (K padded 274->288, 9 ksteps, 16 ct) ============
// slot s = (ct*9+ks)*64 + lam ; elem j: k = 32ks + (lam>>4)*8 + j, col = 16ct + (lam&15)
__global__ void k0b_we1_frag(const float* __restrict__ we1, short* __restrict__ B1f)
{
    int s = blockIdx.x*256 + threadIdx.x;      // < 9216
    int ct = s / (9*64);
    int rem = s - ct*(9*64);
    int ks = rem >> 6, lam = rem & 63;
    int kb = 32*ks + (lam>>4)*8;
    int col = 16*ct + (lam&15);
    float v[8];
    #pragma unroll
    for (int j=0;j<8;++j){
        int k = kb + j;
        v[j] = (k < S_DIM) ? we1[(size_t)k*H1_DIM + col] : 0.f;
    }
    bf16x8 p = pack8(v);
    *(bf16x8*)(B1f + (size_t)s*8) = p;
}

// ============ k0c: [we2 | W2K] -> B2 frag layout (816 cols = 51 ct, 8 ksteps) ============
__global__ void k0c_we2_frag(const float* __restrict__ we2, const float* __restrict__ W2K,
                             short* __restrict__ B2f)
{
    int s = blockIdx.x*256 + threadIdx.x;      // < 26112
    int ct = s / (8*64);
    int rem = s - ct*(8*64);
    int ks = rem >> 6, lam = rem & 63;
    int kb = 32*ks + (lam>>4)*8;
    int col = 16*ct + (lam&15);
    float v[8];
    #pragma unroll
    for (int j=0;j<8;++j){
        int k = kb + j;
        v[j] = (col < 768) ? we2[(size_t)k*768 + col] : W2K[k*48 + (col-768)];
    }
    bf16x8 p = pack8(v);
    *(bf16x8*)(B2f + (size_t)s*8) = p;
}

// ============ k1: MFMA GEMM1 (direct-global B, no LDS staging, no barriers) ============
// block = 128 rows, 4 waves, wave tile 32 rows (2 rt) x 256 cols (16 ct), K = 288 (9 ksteps)
__global__ __launch_bounds__(256, 2)
void k1_h1_aux(const float* __restrict__ state, const short* __restrict__ B1f,
               const float* __restrict__ be1, const float* __restrict__ lng,
               const float* __restrict__ lnb, const float* __restrict__ wt,
               const float* __restrict__ bt,  const float* __restrict__ wc,
               const float* __restrict__ bc,  const float* __restrict__ crisis_bias,
               const float* __restrict__ Kn,
               short* __restrict__ h1b, float* __restrict__ crisL, float* __restrict__ dsimO)
{
    __shared__ short eLds[4][4096];            // 4 wave regions of 8KB (16 rows x 256 cols bf16)
    const int tid  = threadIdx.x;
    const int lane = tid & 63, w = tid >> 6;
    const int grp  = lane >> 4;
    const int row0 = blockIdx.x * 128;

    // ---------- aux: crisis + dsim (2 threads/row) ----------
    {
        const int r = tid >> 1, part = tid & 1;
        const float* srow = state + (size_t)(row0 + r) * S_DIM;
        float bal = srow[0];
        float sp = 0.f;
        for (int q = 1; q <= 30; ++q) sp += srow[q];
        float pmean = sp * (1.0f/30.0f);
        float sv = 0.f, tv = bal;
        for (int q = 1; q <= 30; ++q){
            float p = srow[q];
            float d = p - pmean; sv = fmaf(d,d,sv);
            tv = fmaf(p, srow[q+30], tv);
        }
        float pstd = sqrtf(sv * (1.0f/29.0f)) + 1e-8f;
        float cash = bal / (tv + 1e-8f);
        float mf[12];
        mf[0]=bal; mf[1]=pmean; mf[2]=pstd; mf[3]=cash;
        mf[4]=srow[61];  mf[5]=srow[91];   mf[6]=srow[121]; mf[7]=srow[151];
        mf[8]=srow[181]; mf[9]=srow[211];  mf[10]=srow[241]; mf[11]=srow[271];
        float csum=0.f, nsum=0.f;
        float ssum[M_POP];
        #pragma unroll
        for (int jj=0;jj<M_POP;++jj) ssum[jj]=0.f;
        const float4* wt4 = (const float4*)wt;
        const float4* bt4 = (const float4*)bt;
        const float4* wc4 = (const float4*)wc;
        const float4* Kn4 = (const float4*)Kn;
        for (int dq = 0; dq < 16; ++dq){
            int qi = part*16 + dq;
            float4 a = bt4[qi];
            #pragma unroll
            for (int f = 0; f < 12; ++f){
                float4 wv = wt4[f*32 + qi];
                a.x = fmaf(mf[f],wv.x,a.x); a.y = fmaf(mf[f],wv.y,a.y);
                a.z = fmaf(mf[f],wv.z,a.z); a.w = fmaf(mf[f],wv.w,a.w);
            }
            a.x=fmaxf(a.x,0.f); a.y=fmaxf(a.y,0.f); a.z=fmaxf(a.z,0.f); a.w=fmaxf(a.w,0.f);
            float4 cv = wc4[qi];
            csum += a.x*cv.x + a.y*cv.y + a.z*cv.z + a.w*cv.w;
            nsum += a.x*a.x + a.y*a.y + a.z*a.z + a.w*a.w;
            #pragma unroll
            for (int jj=0;jj<M_POP;++jj){
                float4 kv = Kn4[jj*32 + qi];
                ssum[jj] += a.x*kv.x + a.y*kv.y + a.z*kv.z + a.w*kv.w;
            }
        }
        csum += __shfl_xor(csum, 1, 64);
        nsum += __shfl_xor(nsum, 1, 64);
        #pragma unroll
        for (int jj=0;jj<M_POP;++jj) ssum[jj] += __shfl_xor(ssum[jj], 1, 64);
        if (part == 0){
            float cb  = sigmf(csum + bc[0]);
            float dss = sigmf(srow[272]*10.0f);
            float cvs = sigmf(fabsf(srow[273])*50.0f);
            crisL[row0+r] = 0.6f*cb + 0.25f*dss + 0.15f*cvs + crisis_bias[0];
            float invd = 1.0f/(sqrtf(nsum) + 1e-8f);
            #pragma unroll
            for (int jj=0;jj<M_POP;++jj) dsimO[(size_t)(row0+r)*M_POP + jj] = ssum[jj]*invd;
        }
    }

    // ---------- A fragments from state (fp32 -> bf16), K padded to 288 ----------
    bf16x8 Af[2][9];
    #pragma unroll
    for (int rt=0;rt<2;++rt){
        int row = row0 + w*32 + rt*16 + (lane&15);
        const float* sp = state + (size_t)row*S_DIM;
        #pragma unroll
        for (int ks=0;ks<9;++ks){
            float v[8];
            int kb = 32*ks + grp*8;
            if (ks < 8){
                #pragma unroll
                for (int h=0;h<4;++h){
                    float2 t2 = *(const float2*)(sp + kb + 2*h);
                    v[2*h] = t2.x; v[2*h+1] = t2.y;
                }
            } else {
                #pragma unroll
                for (int j2=0;j2<8;++j2) v[j2]=0.f;
                if (grp < 2){
                    #pragma unroll
                    for (int h=0;h<4;++h){
                        float2 t2 = *(const float2*)(sp + kb + 2*h);
                        v[2*h] = t2.x; v[2*h+1] = t2.y;
                    }
                } else if (grp == 2){
                    float2 t2 = *(const float2*)(sp + 272);
                    v[0] = t2.x; v[1] = t2.y;
                }
            }
            Af[rt][ks] = pack8(v);
        }
    }

    // ---------- GEMM main loop: direct-global B frags ----------
    f32x4 acc[2][16];
    #pragma unroll
    for (int rt=0;rt<2;++rt)
        #pragma unroll
        for (int ct=0;ct<16;++ct) acc[rt][ct] = (f32x4){0.f,0.f,0.f,0.f};

    const short* bb = B1f + (size_t)lane*8;
    #pragma unroll
    for (int ks=0; ks<9; ++ks){
        #pragma unroll
        for (int g=0; g<2; ++g){
            bf16x8 bf[8];
            #pragma unroll
            for (int q=0;q<8;++q){
                int ct = g*8+q;
                bf[q] = *(const bf16x8*)(bb + (size_t)ct*4608 + ks*512);
            }
            #pragma unroll
            for (int q=0;q<8;++q){
                int ct = g*8+q;
                acc[0][ct] = __builtin_amdgcn_mfma_f32_16x16x32_bf16(Af[0][ks], bf[q], acc[0][ct], 0,0,0);
                acc[1][ct] = __builtin_amdgcn_mfma_f32_16x16x32_bf16(Af[1][ks], bf[q], acc[1][ct], 0,0,0);
            }
        }
    }

    // ---------- bias + LN + relu -> bf16 h1 (per-wave LDS transpose) ----------
    const int wbase = w;
    #pragma unroll
    for (int rt=0;rt<2;++rt){
        float s[4] = {0.f,0.f,0.f,0.f};
        float sq[4] = {0.f,0.f,0.f,0.f};
        #pragma unroll
        for (int ct=0;ct<16;++ct){
            float be = be1[ct*16 + (lane&15)];
            #pragma unroll
            for (int r=0;r<4;++r){
                float h = acc[rt][ct][r] + be;
                acc[rt][ct][r] = h;
                s[r] += h; sq[r] = fmaf(h,h,sq[r]);
            }
        }
        #pragma unroll
        for (int mk=1; mk<=8; mk<<=1){
            #pragma unroll
            for (int r=0;r<4;++r){ s[r] += __shfl_xor(s[r],mk,64); sq[r] += __shfl_xor(sq[r],mk,64); }
        }
        float rstd[4], mu[4];
        #pragma unroll
        for (int r=0;r<4;++r){
            mu[r] = s[r] * (1.0f/256.0f);
            float var = sq[r]*(1.0f/256.0f) - mu[r]*mu[r];
            rstd[r] = rsqrtf(var + 1e-5f);
        }
        #pragma unroll
        for (int ct=0;ct<16;++ct){
            int col = ct*16 + (lane&15);
            float g = lng[col], bb2 = lnb[col];
            #pragma unroll
            for (int r=0;r<4;++r){
                float v = (acc[rt][ct][r]-mu[r])*rstd[r]*g + bb2;
                v = fmaxf(v, 0.f);
                eLds[wbase][((grp*4)+r)*256 + col] = (short)f2bf(v);
            }
        }
        // copy out 16 rows (8KB) coalesced
        int rowStart = row0 + w*32 + rt*16;
        #pragma unroll
        for (int i=0;i<8;++i){
            float4 d4 = *(const float4*)&eLds[wbase][(i*64 + lane)*8];
            *(float4*)(h1b + (size_t)rowStart*256 + (i*64+lane)*8) = d4;
        }
    }
}

// ============ k2: MFMA GEMM2 direct-global B (768 E cols + 48 sim cols) ============
template<int NCT>
__device__ __forceinline__ void k2_gemm_pass(f32x4 (&acc)[2][16], const bf16x8 (&Af)[2][8],
        const short* __restrict__ pb)
{
    #pragma unroll
    for (int rt=0;rt<2;++rt)
        #pragma unroll
        for (int ct=0;ct<NCT;++ct) acc[rt][ct] = (f32x4){0.f,0.f,0.f,0.f};
    #pragma unroll
    for (int ks=0; ks<8; ++ks){
        #pragma unroll
        for (int g=0; g<(NCT+7)/8; ++g){
            bf16x8 bf[8];
            #pragma unroll
            for (int q=0;q<8;++q){
                int ct = g*8+q;
                if (ct < NCT)
                    bf[q] = *(const bf16x8*)(pb + (size_t)ct*4096 + ks*512);
            }
            #pragma unroll
            for (int q=0;q<8;++q){
                int ct = g*8+q;
                if (ct < NCT){
                    acc[0][ct] = __builtin_amdgcn_mfma_f32_16x16x32_bf16(Af[0][ks], bf[q], acc[0][ct], 0,0,0);
                    acc[1][ct] = __builtin_amdgcn_mfma_f32_16x16x32_bf16(Af[1][ks], bf[q], acc[1][ct], 0,0,0);
                }
            }
        }
    }
}

__global__ __launch_bounds__(256, 2)
void k2_emb_sink_out(const short* __restrict__ h1b, const short* __restrict__ B2f,
                     const float* __restrict__ be2, const float* __restrict__ bK,
                     const float* __restrict__ conc, const float* __restrict__ crisL,
                     const float* __restrict__ dsimI, const float* __restrict__ fitness,
                     const float* __restrict__ w_prev, float* __restrict__ out)
{
    __shared__ float sNrm[128*9];
    __shared__ float sSim[128*49];
    __shared__ float sConc[M_POP*A_DIM];
    __shared__ float sAct[128*A_DIM];
    const int tid  = threadIdx.x;
    const int lane = tid & 63, w = tid >> 6;
    const int grp  = lane >> 4;
    const int row0 = blockIdx.x * 128;

    for (int q = tid; q < M_POP*A_DIM; q += 256) sConc[q] = conc[q];

    // A fragments from bf16 h1 (registers, reused across all passes)
    bf16x8 Af[2][8];
    #pragma unroll
    for (int rt=0;rt<2;++rt){
        int row = row0 + w*32 + rt*16 + (lane&15);
        #pragma unroll
        for (int ks=0;ks<8;++ks)
            Af[rt][ks] = *(const bf16x8*)(h1b + (size_t)row*256 + 32*ks + grp*8);
    }

    const short* bbase = B2f + (size_t)lane*8;
    f32x4 acc[2][16];
    // ---- 3 E passes: accumulate per-panel normsq only ----
    #pragma unroll 1
    for (int pass=0; pass<3; ++pass){
        k2_gemm_pass<16>(acc, Af, bbase + (size_t)pass*65536);
        float nsq[2][4][2];
        #pragma unroll
        for (int rt=0;rt<2;++rt)
            #pragma unroll
            for (int r=0;r<4;++r){ nsq[rt][r][0]=0.f; nsq[rt][r][1]=0.f; }
        #pragma unroll
        for (int ct=0;ct<16;++ct){
            float be = be2[pass*256 + ct*16 + (lane&15)];
            const int hh = ct >> 3;
            #pragma unroll
            for (int rt=0;rt<2;++rt)
                #pragma unroll
                for (int r=0;r<4;++r){
                    float e = acc[rt][ct][r] + be;
                    nsq[rt][r][hh] = fmaf(e,e,nsq[rt][r][hh]);
                }
        }
        #pragma unroll
        for (int mk=1; mk<=8; mk<<=1){
            #pragma unroll
            for (int rt=0;rt<2;++rt)
                #pragma unroll
                for (int r=0;r<4;++r){
                    nsq[rt][r][0] += __shfl_xor(nsq[rt][r][0],mk,64);
                    nsq[rt][r][1] += __shfl_xor(nsq[rt][r][1],mk,64);
                }
        }
        if ((lane&15) < 2){
            int panel = 2*pass + (lane&15);
            #pragma unroll
            for (int rt=0;rt<2;++rt)
                #pragma unroll
                for (int r=0;r<4;++r){
                    int row = w*32 + rt*16 + grp*4 + r;
                    sNrm[row*9 + panel] = nsq[rt][r][lane&15];
                }
        }
    }
    // ---- sim pass (48 folded cols) ----
    k2_gemm_pass<3>(acc, Af, bbase + (size_t)3*65536);
    #pragma unroll
    for (int ct=0;ct<3;++ct){
        float bKv = bK[ct*16 + (lane&15)];
        #pragma unroll
        for (int rt=0;rt<2;++rt)
            #pragma unroll
            for (int r=0;r<4;++r){
                int row = w*32 + rt*16 + grp*4 + r;
                sSim[row*49 + ct*16 + (lane&15)] = acc[rt][ct][r] + bKv;
            }
    }
    __syncthreads();

    // ---- per-row sinkhorn + blend + action ----
    if (tid < 128){
        const int grow = row0 + tid;
        float invn[M_EMB];
        #pragma unroll
        for (int i=0;i<M_EMB;++i) invn[i] = 1.0f/(sqrtf(sNrm[tid*9+i]) + 1e-8f);
        float logK[M_EMB][M_POP];
        #pragma unroll
        for (int i=0;i<M_EMB;++i){
            #pragma unroll
            for (int jj=0;jj<M_POP;++jj){
                float sim = sSim[tid*49 + i*8 + jj]*invn[i];
                float C = 1.0f - sim - 0.1f*dsimI[(size_t)grow*M_POP + jj];
                logK[i][jj] = -20.0f*C;
            }
        }
        const float LOG_MU = -1.7917594692280550f;
        const float LOG_NU = -2.0794415416798357f;
        float u[M_EMB], v[M_POP];
        #pragma unroll
        for (int i=0;i<M_EMB;++i) u[i]=0.f;
        #pragma unroll
        for (int jj=0;jj<M_POP;++jj) v[jj]=0.f;
        for (int it=0; it<10; ++it){
            #pragma unroll
            for (int i=0;i<M_EMB;++i){
                float mx = -1e30f;
                #pragma unroll
                for (int jj=0;jj<M_POP;++jj) mx = fmaxf(mx, logK[i][jj]+v[jj]);
                float sum = 0.f;
                #pragma unroll
                for (int jj=0;jj<M_POP;++jj) sum += __expf(logK[i][jj]+v[jj]-mx);
                u[i] = LOG_MU - (mx + __logf(sum));
            }
            #pragma unroll
            for (int jj=0;jj<M_POP;++jj){
                float mx = -1e30f;
                #pragma unroll
                for (int i=0;i<M_EMB;++i) mx = fmaxf(mx, logK[i][jj]+u[i]);
                float sum = 0.f;
                #pragma unroll
                for (int i=0;i<M_EMB;++i) sum += __expf(logK[i][jj]+u[i]-mx);
                v[jj] = LOG_NU - (mx + __logf(sum));
            }
        }
        float wot[M_POP]; float wsum = 0.f;
        #pragma unroll
        for (int jj=0;jj<M_POP;++jj){
            float sum = 0.f;
            #pragma unroll
            for (int i=0;i<M_EMB;++i) sum += __expf(logK[i][jj]+u[i]+v[jj]);
            wot[jj]=sum; wsum += sum;
        }
        float invw = 1.0f/(wsum + 1e-8f);
        float cl = crisL[grow];
        float eta = 0.05f + 0.15f*cl;
        float wrep[M_POP]; float rsum=0.f;
        #pragma unroll
        for (int jj=0;jj<M_POP;++jj){
            wrep[jj] = w_prev[jj]*__expf(eta*fitness[(size_t)grow*M_POP+jj]);
            rsum += wrep[jj];
        }
        float invr = 1.0f/(rsum + 1e-8f);
        float al = fminf(fmaxf(0.3f - 0.24f*cl, 0.06f), 0.3f);
        float wv[M_POP]; float ws2=0.f;
        #pragma unroll
        for (int jj=0;jj<M_POP;++jj){
            wv[jj] = (1.0f-al)*wrep[jj]*invr + al*wot[jj]*invw;
            ws2 += wv[jj];
        }
        float invw2 = 1.0f/(ws2 + 1e-8f);
        #pragma unroll
        for (int jj=0;jj<M_POP;++jj) wv[jj] *= invw2;
        float mc[A_DIM]; float mmax = -1e30f;
        #pragma unroll
        for (int a=0;a<A_DIM;++a){
            float sum = 1.0f;
            #pragma unroll
            for (int jj=0;jj<M_POP;++jj) sum = fmaf(wv[jj], sConc[jj*A_DIM+a], sum);
            mc[a]=sum; mmax = fmaxf(mmax, sum);
        }
        float es = 0.f;
        #pragma unroll
        for (int a=0;a<A_DIM;++a){ mc[a] = __expf(mc[a]-mmax); es += mc[a]; }
        float inve = 1.0f/es;
        float s3 = 0.f;
        #pragma unroll
        for (int a=0;a<A_DIM;++a){ mc[a] *= inve; s3 += mc[a]; }
        float invf = 1.0f/(s3 + 1e-8f);
        #pragma unroll
        for (int a=0;a<A_DIM;++a) sAct[tid*A_DIM + a] = mc[a]*invf;
    }
    __syncthreads();
    for (int q = tid; q < 128*A_DIM; q += 256)
        out[(size_t)row0*A_DIM + q] = sAct[q];
}

extern "C" void kernel_launch(void* const* d_in, const int* in_sizes, int n_in,
                              void* d_out, int out_size, void* d_ws, size_t ws_size,
                              hipStream_t stream)
{
    const float* state       = (const float*)d_in[0];
    const float* fitness     = (const float*)d_in[1];
    const float* we1         = (const float*)d_in[2];
    const float* be1         = (const float*)d_in[3];
    const float* lng         = (const float*)d_in[4];
    const float* lnb         = (const float*)d_in[5];
    const float* we2         = (const float*)d_in[6];
    const float* be2         = (const float*)d_in[7];
    const float* proto       = (const float*)d_in[8];
    const float* wd1         = (const float*)d_in[9];
    const float* bd1         = (const float*)d_in[10];
    const float* wd2         = (const float*)d_in[11];
    const float* bd2         = (const float*)d_in[12];
    const float* wt          = (const float*)d_in[13];
    const float* bt          = (const float*)d_in[14];
    // d_in[15]=wz, d_in[16]=bz dead code
    const float* wc          = (const float*)d_in[17];
    const float* bc          = (const float*)d_in[18];
    const float* w_prev      = (const float*)d_in[19];
    const float* crisis_bias = (const float*)d_in[20];

    float* ws = (float*)d_ws;
    short* h1b   = (short*)ws;                                  // bf16 [B][256] = B*128 floats
    float* crisL = ws + (size_t)B_TOT*128;                      // B
    float* dsim  = crisL + B_TOT;                               // B*8
    float* Kn    = dsim + (size_t)B_TOT*8;                      // 1024
    float* conc  = Kn + 1024;                                   // 240 (+16)
    float* W2K   = conc + 256;                                  // 12288
    float* bK    = W2K + 12288;                                 // 48 (+16)
    short* B1f   = (short*)(bK + 64);                           // 73728 bf16 = 36864 floats
    short* B2f   = (short*)(bK + 64 + 36864);                   // 208896 bf16
    float* outp  = (float*)d_out;

    k0a_kn<<<1, 256, 0, stream>>>(proto, Kn);
    k0h_conc<<<8, 128, 0, stream>>>(proto, wd1, bd1, wd2, bd2, conc);
    k0w_w2k<<<49, 256, 0, stream>>>(we2, be2, Kn, W2K, bK);
    k0b_we1_frag<<<36, 256, 0, stream>>>(we1, B1f);
    k0c_we2_frag<<<102, 256, 0, stream>>>(we2, W2K, B2f);
    k1_h1_aux<<<B_TOT/128, 256, 0, stream>>>(state, B1f, be1, lng, lnb,
                                             wt, bt, wc, bc, crisis_bias, Kn,
                                             h1b, crisL, dsim);
    k2_emb_sink_out<<<B_TOT/128, 256, 0, stream>>>(h1b, B2f, be2, bK, conc,
                                                   crisL, dsim, fitness, w_prev, outp);
}